// Round 5
// baseline (7429.644 us; speedup 1.0000x reference)
//
#include <hip/hip_runtime.h>

typedef unsigned long long u64;
typedef unsigned int u32;
typedef unsigned short ushort_t;

#define HH 200
#define WW 200
#define HWP 40000          // 200*200 pixels
#define NANCH 360000       // HWP * 9
#define PRE 6000
#define POST 300
#define NW 94              // 64-bit mask words per NMS row (ceil(6000/64))
#define NBINS 16384
#define KCAP 8192
#define LSTRIDE 40         // LDS row stride in ushorts (80B): 16B aligned, min-aliasing b128

typedef __attribute__((ext_vector_type(8))) short bf16x8;
typedef __attribute__((ext_vector_type(4))) float f32x4;

// ---------------- workspace layout (same footprint as round 1 + 18KB table) ----
static constexpr size_t X_F    = 0;                          // conv1 output x[512][40000] (+64 slack)
static constexpr size_t X_CNT  = 512ULL*HWP + 64;
static constexpr size_t W1B_F  = X_F + X_CNT;                // packed B planes 1+2: 4.72M ushorts = 2.36M floats
static constexpr size_t WT64_F = W1B_F + 4608ULL*512;        // packed cls/loc weights [512][64]
static constexpr size_t B64_F  = WT64_F + 512ULL*64;         // packed bias [64]
static constexpr size_t SC_F   = B64_F + 64;                 // scores [360000]
static constexpr size_t ROI_F  = SC_F + NANCH;               // decoded boxes [360000][4] (B plane 3 overlays pre-decode)
static constexpr size_t BOX_F  = ROI_F + 4ULL*NANCH;         // top-6000 boxes (pad 6016) [4]
static constexpr size_t FEND_F = BOX_F + 6016ULL*4;
static constexpr size_t HIST_B = ((FEND_F*4 + 255)/256)*256; // u32[16384]
static constexpr size_t CTRL_B = HIST_B + NBINS*4;           // u32[64]: [0]=cnt, [1]=cutoff bucket
static constexpr size_t KEY_B  = CTRL_B + 256;               // u64[8192] candidate keys
static constexpr size_t SORT_B = KEY_B + (size_t)KCAP*8;     // u64[6016] sorted keys
static constexpr size_t VALW_B = SORT_B + 6016ULL*8;         // u64[94] validity bits
static constexpr size_t MASK_B = ((VALW_B + NW*8 + 255)/256)*256; // u64[6000][94] NMS mask
static constexpr size_t OFFT_B = MASK_B + (size_t)PRE*NW*8;  // u32[4608] A-gather offset table
static constexpr size_t WS_END = OFFT_B + 4608ULL*4;         // ~103.5 MB total

// ---------------- helpers ----------------
__device__ __forceinline__ u32 fsort(float f) {
  u32 u = __float_as_uint(f);
  return (u & 0x80000000u) ? ~u : (u | 0x80000000u);
}
__device__ __forceinline__ int bucket_of(float s) {
  int b = (int)((s + 1.0f) * 8191.0f);
  return b < 0 ? 0 : (b > 16383 ? 16383 : b);
}

// ---------------- K0a: prepack w1 -> 3 exact bf16 slices, scattered into per-wave
// fragment order: p12[(((z*144+s)*2+wnb)*4+j)*1024 + p*512 + lane*8 + e]  (p in {0,1})
//                 p3 [(((z*144+s)*2+wnb)*4+j)*512  + lane*8 + e]
// so conv waves load B fragments directly from global, coalesced, no LDS.
__global__ void pack_w1b(const float* __restrict__ w1, ushort_t* __restrict__ p12,
                         ushort_t* __restrict__ p3) {
  int idx = blockIdx.x*256 + threadIdx.x;
  if (idx >= 512*4608) return;
  int och = idx / 4608, k = idx - (idx/4608)*4608;   // k = ci*9 + tap (reference order)
  float f = w1[idx];
  u32 u = __float_as_uint(f);
  float d = f - __uint_as_float(u & 0xffff0000u);
  u32 v = __float_as_uint(d);
  float e2 = d - __uint_as_float(v & 0xffff0000u);
  u32 w = __float_as_uint(e2);
  ushort_t h1 = (ushort_t)(u >> 16), h2 = (ushort_t)(v >> 16), h3 = (ushort_t)(w >> 16);
  int z = och >> 7, oz = och & 127;
  int wnb = oz >> 6, j = (oz >> 4) & 3, lm = oz & 15;
  int s = k >> 5, kk = k & 31, lg = kk >> 3, e = kk & 7;
  int lane = lg*16 + lm;
  size_t base = (((size_t)z*144 + s)*2 + wnb)*4 + j;
  p12[base*1024 +       lane*8 + e] = h1;
  p12[base*1024 + 512 + lane*8 + e] = h2;
  p3 [base*512  +       lane*8 + e] = h3;
}

// ---------------- K0c: A-gather offset table: offTab[k] = ((ci*HWP+dy*200+dx+256)<<4)|tap ----
__global__ void init_offtab(u32* __restrict__ offTab) {
  int k = blockIdx.x*256 + threadIdx.x;
  if (k >= 4608) return;
  int ci = k/9, tap = k - ci*9;
  int dy = tap/3 - 1, dx = tap - (tap/3)*3 - 1;
  int off = ci*HWP + dy*200 + dx;
  offTab[k] = ((u32)(off + 256) << 4) | (u32)tap;
}

// ---------------- K0b: pack wc(18)/wl(36) -> wt[ci][64] (zero-padded), bias[64] ----------------
__global__ void pack_wcl(const float* __restrict__ wc, const float* __restrict__ bc,
                         const float* __restrict__ wl, const float* __restrict__ bl,
                         float* __restrict__ wt, float* __restrict__ b64) {
  int idx = blockIdx.x*256 + threadIdx.x;
  if (idx < 512*64) {
    int ci = idx >> 6, o = idx & 63;
    float v = 0.f;
    if (o < 18) v = wc[o*512 + ci];
    else if (o < 54) v = wl[(o-18)*512 + ci];
    wt[idx] = v;
  } else if (idx < 512*64 + 64) {
    int o = idx - 512*64;
    float v = 0.f;
    if (o < 18) v = bc[o]; else if (o < 54) v = bl[o-18];
    b64[o] = v;
  }
}

// ---------------- K1: 3x3 conv 512->512 + ReLU, exact bf16x3 split, 6-product MFMA ----------
// A staged via LDS (3 planes, 30.7KB -> 5 blocks/CU); B fragments loaded DIRECTLY from
// global (prepacked per-wave order). A-gather addresses via scalar offset table.
__global__ __launch_bounds__(256, 5) void conv3x3_mfma(const float* __restrict__ feat,
    const ushort_t* __restrict__ p12, const ushort_t* __restrict__ p3,
    const u32* __restrict__ offTab,
    const float* __restrict__ b1, float* __restrict__ xout) {
  __shared__ ushort_t A1[128*LSTRIDE], A2[128*LSTRIDE], A3[128*LSTRIDE];
  const int t = threadIdx.x;
  const int x0 = blockIdx.x*16, y0 = blockIdx.y*8;
  const int zi = blockIdx.z;
  const int ob = zi*128;
  const int m  = t & 127;                               // staging row (pixel)
  const int hU = __builtin_amdgcn_readfirstlane(t >> 7); // wave-uniform k-half selector
  const int myrow = m >> 4, mxcol = m & 15;
  const int py = y0 + myrow, px = x0 + mxcol;
  const int pixoff = py*200 + px;

  // per-thread 9-bit tap validity mask
  u32 vmask9 = 0;
  #pragma unroll
  for (int tap = 0; tap < 9; ++tap) {
    int dy = tap/3 - 1, dx = tap - (tap/3)*3 - 1;
    if ((unsigned)(py + dy) < 200u && (unsigned)(px + dx) < 200u) vmask9 |= (1u << tap);
  }

  f32x4 acc[4][4];
  #pragma unroll
  for (int i = 0; i < 4; ++i)
    #pragma unroll
    for (int j = 0; j < 4; ++j) acc[i][j] = (f32x4){0.f, 0.f, 0.f, 0.f};

  const int wave = t >> 6, lane = t & 63;
  const int wm = (wave & 1)*64, wnb = wave >> 1;
  const int lm = lane & 15, lg = lane >> 4;
  const u32* offp = offTab + 16*hU;

  for (int s = 0; s < 144; ++s) {
    // ---- B fragments: 12 coalesced 16B global loads straight to registers ----
    bf16x8 fb1[4], fb2[4], fb3[4];
    {
      const ushort_t* pb12 = p12 + ((((size_t)zi*144 + s)*2 + wnb)*4096) + lane*8;
      const ushort_t* pb3  = p3  + ((((size_t)zi*144 + s)*2 + wnb)*2048) + lane*8;
      #pragma unroll
      for (int j = 0; j < 4; ++j) {
        fb1[j] = *(const bf16x8*)(pb12 + j*1024);
        fb2[j] = *(const bf16x8*)(pb12 + j*1024 + 512);
        fb3[j] = *(const bf16x8*)(pb3  + j*512);
      }
    }
    // ---- A staging: 16 gathers (scalar-table addresses) -> 3 slices -> 6 ds_write_b128 ----
    {
      const u32* op = offp + s*32;
      u32 q1[8], q2[8], q3[8];
      #pragma unroll
      for (int j2 = 0; j2 < 8; ++j2) {
        float fv[2];
        #pragma unroll
        for (int e = 0; e < 2; ++e) {
          u32 ent = op[2*j2 + e];               // scalar load (wave-uniform index)
          int soff = (int)(ent >> 4) - 256;     // scalar
          u32 tap  = ent & 15u;                 // scalar
          bool ok  = ((vmask9 >> tap) & 1u) != 0;
          int voff = ok ? (soff + pixoff) : 0;
          float f = feat[voff];
          fv[e] = ok ? f : 0.f;
        }
        u32 u0 = __float_as_uint(fv[0]), u1 = __float_as_uint(fv[1]);
        q1[j2] = (u0 >> 16) | (u1 & 0xffff0000u);
        float d0 = fv[0] - __uint_as_float(u0 & 0xffff0000u);
        float d1 = fv[1] - __uint_as_float(u1 & 0xffff0000u);
        u32 v0 = __float_as_uint(d0), v1 = __float_as_uint(d1);
        q2[j2] = (v0 >> 16) | (v1 & 0xffff0000u);
        float e0 = d0 - __uint_as_float(v0 & 0xffff0000u);
        float e1 = d1 - __uint_as_float(v1 & 0xffff0000u);
        u32 w0 = __float_as_uint(e0), w1v = __float_as_uint(e1);
        q3[j2] = (w0 >> 16) | (w1v & 0xffff0000u);
      }
      *(uint4*)&A1[m*LSTRIDE + 16*hU    ] = make_uint4(q1[0], q1[1], q1[2], q1[3]);
      *(uint4*)&A1[m*LSTRIDE + 16*hU + 8] = make_uint4(q1[4], q1[5], q1[6], q1[7]);
      *(uint4*)&A2[m*LSTRIDE + 16*hU    ] = make_uint4(q2[0], q2[1], q2[2], q2[3]);
      *(uint4*)&A2[m*LSTRIDE + 16*hU + 8] = make_uint4(q2[4], q2[5], q2[6], q2[7]);
      *(uint4*)&A3[m*LSTRIDE + 16*hU    ] = make_uint4(q3[0], q3[1], q3[2], q3[3]);
      *(uint4*)&A3[m*LSTRIDE + 16*hU + 8] = make_uint4(q3[4], q3[5], q3[6], q3[7]);
    }
    __syncthreads();
    // ---- compute: 12 ds_read_b128 + 96 MFMA per wave ----
    bf16x8 fa1[4], fa2[4], fa3[4];
    #pragma unroll
    for (int i = 0; i < 4; ++i) {
      int ra = (wm + i*16 + lm)*LSTRIDE + lg*8;
      fa1[i] = *(const bf16x8*)&A1[ra];
      fa2[i] = *(const bf16x8*)&A2[ra];
      fa3[i] = *(const bf16x8*)&A3[ra];
    }
    #pragma unroll
    for (int i = 0; i < 4; ++i)
      #pragma unroll
      for (int j = 0; j < 4; ++j) {
        acc[i][j] = __builtin_amdgcn_mfma_f32_16x16x32_bf16(fa1[i], fb1[j], acc[i][j], 0, 0, 0);
        acc[i][j] = __builtin_amdgcn_mfma_f32_16x16x32_bf16(fa1[i], fb2[j], acc[i][j], 0, 0, 0);
        acc[i][j] = __builtin_amdgcn_mfma_f32_16x16x32_bf16(fa2[i], fb1[j], acc[i][j], 0, 0, 0);
        acc[i][j] = __builtin_amdgcn_mfma_f32_16x16x32_bf16(fa1[i], fb3[j], acc[i][j], 0, 0, 0);
        acc[i][j] = __builtin_amdgcn_mfma_f32_16x16x32_bf16(fa2[i], fb2[j], acc[i][j], 0, 0, 0);
        acc[i][j] = __builtin_amdgcn_mfma_f32_16x16x32_bf16(fa3[i], fb1[j], acc[i][j], 0, 0, 0);
      }
    __syncthreads();
  }

  // epilogue: bias + relu, store x[och][pixel]
  #pragma unroll
  for (int i = 0; i < 4; ++i) {
    int prow = wm + i*16 + lg*4;
    #pragma unroll
    for (int j = 0; j < 4; ++j) {
      int o = ob + wnb*64 + j*16 + lm;
      float bias = b1[o];
      #pragma unroll
      for (int r = 0; r < 4; ++r) {
        int p  = prow + r;
        int yy = y0 + (p >> 4), xx = x0 + (p & 15);
        if (xx < WW) {
          xout[(size_t)o*HWP + yy*200 + xx] = fmaxf(acc[i][j][r] + bias, 0.f);
        }
      }
    }
  }
}

// ---------------- K2: 1x1 convs (cls+loc) as GEMM [40000 x 64] = x^T[40000x512] * wt[512x64] ----
__global__ __launch_bounds__(256, 4) void conv1x1(const float* __restrict__ x,
                                                  const float* __restrict__ wt,
                                                  const float* __restrict__ bias,
                                                  float* __restrict__ out) {
  __shared__ float Xs[16*128];
  __shared__ float Ws[16*64];
  const int t = threadIdx.x;
  const int m0 = blockIdx.x*128;
  float acc[32];
  #pragma unroll
  for (int i = 0; i < 32; ++i) acc[i] = 0.f;
  const int mb = t & 15, nb = t >> 4;
  const int mm = t & 127, hh = t >> 7;
  const int nn = t & 63,  h2 = t >> 6;

  for (int kb = 0; kb < 512; kb += 16) {
    #pragma unroll
    for (int j = 0; j < 8; ++j) {
      int kk = hh + 2*j;
      Xs[kk*128 + mm] = x[(size_t)(kb+kk)*HWP + m0 + mm];
    }
    #pragma unroll
    for (int j = 0; j < 4; ++j) {
      int kk = h2 + 4*j;
      Ws[kk*64 + nn] = wt[(size_t)(kb+kk)*64 + nn];
    }
    __syncthreads();
    #pragma unroll
    for (int kk = 0; kk < 16; ++kk) {
      float av[8], bv[4];
      *(float4*)&av[0] = *(const float4*)&Xs[kk*128 + mb*8];
      *(float4*)&av[4] = *(const float4*)&Xs[kk*128 + mb*8 + 4];
      *(float4*)&bv[0] = *(const float4*)&Ws[kk*64 + nb*4];
      #pragma unroll
      for (int i = 0; i < 8; ++i)
        #pragma unroll
        for (int jj = 0; jj < 4; ++jj)
          acc[i*4+jj] = fmaf(av[i], bv[jj], acc[i*4+jj]);
    }
    __syncthreads();
  }

  #pragma unroll
  for (int jj = 0; jj < 4; ++jj) {
    int o = nb*4 + jj;
    float bv = bias[o];
    #pragma unroll
    for (int i = 0; i < 8; ++i) {
      int mm2 = m0 + mb*8 + i;
      if (mm2 < HWP) {
        float v = acc[i*4+jj] + bv;
        if (o < 18)       out[(size_t)mm2*18 + o] = v;               // pred_cls: [m][2a+c]
        else if (o < 54)  out[720000 + (size_t)mm2*36 + (o-18)] = v; // pred_loc: [m][4a+j]
      }
    }
  }
}

// ---------------- K3: decode boxes + score + histogram ----------------
__global__ void decode(const float* __restrict__ dout, const float* __restrict__ anchor,
                       float* __restrict__ scores, float4* __restrict__ roi, u32* __restrict__ hist) {
  int n = blockIdx.x*256 + threadIdx.x;
  if (n >= NANCH) return;
  int mq = n / 9;
  int a  = n - mq*9;
  float c0 = dout[(size_t)mq*18 + 2*a];
  float c1 = dout[(size_t)mq*18 + 2*a + 1];
  float score = 1.0f / (1.0f + expf(c0 - c1));  // == softmax[:,1]; monotone in (c1-c0)
  const float* lp = dout + 720000 + (size_t)mq*36 + 4*a;
  float l0 = lp[0], l1 = lp[1], l2 = lp[2], l3 = lp[3];
  float4 an = ((const float4*)anchor)[n];
  float aw = an.z - an.x, ah = an.w - an.y;
  float acx = (an.x + an.z)*0.5f, acy = (an.y + an.w)*0.5f;
  float cx = l0*aw + acx, cy = l1*ah + acy;
  float bw = expf(l2)*aw, bh = expf(l3)*ah;
  float x1 = fminf(fmaxf(cx - bw*0.5f, 0.f), 1.f);
  float y1 = fminf(fmaxf(cy - bh*0.5f, 0.f), 1.f);
  float x2 = fminf(fmaxf(cx + bw*0.5f, 0.f), 1.f);
  float y2 = fminf(fmaxf(cy + bh*0.5f, 0.f), 1.f);
  bool valid = ((y2 - y1) >= 0.016f) && ((x2 - x1) >= 0.016f);
  float sc = valid ? score : -1.0f;
  scores[n] = sc;
  roi[n] = make_float4(x1, y1, x2, y2);
  atomicAdd(&hist[bucket_of(sc)], 1u);
}

// ---------------- K4: find cutoff bucket B ----------------
__global__ void scan_hist(const u32* __restrict__ hist, u32* __restrict__ ctrl) {
  __shared__ u32 seg[256];
  int t = threadIdx.x;
  u32 s = 0;
  for (int b = 0; b < 64; ++b) s += hist[t*64 + b];
  seg[t] = s;
  __syncthreads();
  if (t == 0) {
    u32 cum = 0; int B = 0;
    for (int sg = 255; sg >= 0; --sg) {
      if (cum + seg[sg] >= PRE) {
        for (int b = sg*64 + 63; b >= sg*64; --b) {
          cum += hist[b];
          if (cum >= PRE) { B = b; break; }
        }
        break;
      }
      cum += seg[sg];
    }
    ctrl[1] = (u32)B;
  }
}

// ---------------- K5: compact candidates (bucket >= B) into keybuf ----------------
__global__ void compact(const float* __restrict__ scores, u32* __restrict__ ctrl, u64* __restrict__ keybuf) {
  int n = blockIdx.x*256 + threadIdx.x;
  if (n >= NANCH) return;
  float s = scores[n];
  int B = (int)ctrl[1];
  if (bucket_of(s) >= B) {
    u32 pos = atomicAdd(&ctrl[0], 1u);
    if (pos < KCAP) {
      keybuf[pos] = ((u64)fsort(s) << 32) | (u64)(0xFFFFFFFFu - (u32)n); // ties: lower n wins
    }
  }
}

// ---------------- K6: single-block bitonic sort of 8192 u64 keys, descending ----------------
__global__ __launch_bounds__(1024) void sortk(const u64* __restrict__ keybuf, const u32* __restrict__ ctrl,
                                              u64* __restrict__ sorted) {
  __shared__ u64 s[KCAP];
  int t = threadIdx.x;
  u32 cnt = ctrl[0]; if (cnt > KCAP) cnt = KCAP;
  for (int i = t; i < KCAP; i += 1024) s[i] = (i < (int)cnt) ? keybuf[i] : 0ULL;
  __syncthreads();
  for (int size = 2; size <= KCAP; size <<= 1) {
    for (int stride = size >> 1; stride > 0; stride >>= 1) {
      for (int w = t; w < KCAP/2; w += 1024) {
        int lo = ((w & ~(stride-1)) << 1) | (w & (stride-1));
        int hi = lo + stride;
        bool desc = ((lo & size) == 0);
        u64 a = s[lo], b = s[hi];
        if ((a < b) == desc) { s[lo] = b; s[hi] = a; }
      }
      __syncthreads();
    }
  }
  for (int i = t; i < 6016; i += 1024) sorted[i] = s[i];
}

// ---------------- K6b: gather top-6000 boxes + validity bits ----------------
__global__ void gather_topk(const u64* __restrict__ sorted, const float4* __restrict__ roi,
                            float4* __restrict__ boxes, u64* __restrict__ validw) {
  int i = blockIdx.x*64 + threadIdx.x;
  bool valid = false;
  float4 b = make_float4(0.f, 0.f, 0.f, 0.f);
  if (i < PRE) {
    u64 k = sorted[i];
    if (k) {
      u32 n = 0xFFFFFFFFu - (u32)(k & 0xFFFFFFFFu);
      if (n < NANCH) { b = roi[n]; valid = (k >> 63) != 0; }
    }
  }
  boxes[i] = b;
  u64 bal = __ballot(valid);
  if (threadIdx.x == 0) validw[blockIdx.x] = bal;
}

// ---------------- K7: NMS suppression bitmask ----------------
__global__ void nms_mask(const float4* __restrict__ boxes, u64* __restrict__ mask) {
  int bi = blockIdx.y, bj = blockIdx.x;
  int t = threadIdx.x;
  int i = bi*64 + t;
  if (bj < bi) {
    if (i < PRE) mask[(size_t)i*NW + bj] = 0ULL;
    return;
  }
  __shared__ float4 cb[64];
  int j0 = bj*64;
  cb[t] = boxes[j0 + t];
  __syncthreads();
  if (i >= PRE) return;
  float4 b = boxes[i];
  float area_i = (b.z - b.x) * (b.w - b.y);
  u64 bits = 0;
  #pragma unroll 4
  for (int jj = 0; jj < 64; ++jj) {
    int j = j0 + jj;
    float4 c = cb[jj];
    float xx1 = fmaxf(b.x, c.x), yy1 = fmaxf(b.y, c.y);
    float xx2 = fminf(b.z, c.z), yy2 = fminf(b.w, c.w);
    float inter = fmaxf(xx2 - xx1, 0.f) * fmaxf(yy2 - yy1, 0.f);
    float area_j = (c.z - c.x) * (c.w - c.y);
    float iou = inter / (area_i + area_j - inter + 1e-12f);
    if (iou > 0.7f && j > i) bits |= (1ULL << jj);
  }
  mask[(size_t)i*NW + bj] = bits;
}

// ---------------- K8: sequential greedy scan + emit first 300 kept boxes ----------------
__global__ void nms_scan(const u64* __restrict__ mask, const u64* __restrict__ validw,
                         const float* __restrict__ boxes, float* __restrict__ rois) {
  int lane = threadIdx.x;
  u64 r0 = ~validw[lane];
  u64 r1 = (lane < NW-64) ? ~validw[64 + lane] : ~0ULL;
  int kept = 0;
  u64 m0 = mask[lane];
  u64 m1 = (lane < NW-64) ? mask[64 + lane] : 0ULL;
  for (int i = 0; i < PRE; ++i) {
    int wi = i >> 6;
    u64 w0 = __shfl(r0, wi & 63);
    u64 w1 = __shfl(r1, wi & 63);
    u64 wv = (wi < 64) ? w0 : w1;
    if (!((wv >> (i & 63)) & 1ULL)) {
      if (lane < 4) rois[kept*4 + lane] = boxes[(size_t)i*4 + lane];
      kept++;
      if (kept >= POST) break;
      r0 |= m0;
      if (lane < NW-64) r1 |= m1;
    }
    if (i + 1 < PRE) {
      m0 = mask[(size_t)(i+1)*NW + lane];
      m1 = (lane < NW-64) ? mask[(size_t)(i+1)*NW + 64 + lane] : 0ULL;
    }
  }
}

extern "C" void kernel_launch(void* const* d_in, const int* in_sizes, int n_in,
                              void* d_out, int out_size, void* d_ws, size_t ws_size,
                              hipStream_t stream) {
  const float* feat   = (const float*)d_in[0];
  const float* anchor = (const float*)d_in[1];
  const float* w1     = (const float*)d_in[2];
  const float* b1     = (const float*)d_in[3];
  const float* wc     = (const float*)d_in[4];
  const float* bc     = (const float*)d_in[5];
  const float* wl     = (const float*)d_in[6];
  const float* bl     = (const float*)d_in[7];
  float* out = (float*)d_out;
  char*  ws  = (char*)d_ws;
  float* wsf = (float*)d_ws;

  if (ws_size < WS_END*4 && ws_size < WS_END) return;  // need ~103.5 MB

  float*    x      = wsf + X_F;
  ushort_t* p12    = (ushort_t*)(wsf + W1B_F);   // packed B planes 1+2 (9.44 MB)
  ushort_t* p3     = (ushort_t*)(wsf + ROI_F);   // packed B plane 3 overlays roi (dead pre-decode)
  float*    wt64   = wsf + WT64_F;
  float*    b64    = wsf + B64_F;
  float*    scores = wsf + SC_F;
  float4*   roi    = (float4*)(wsf + ROI_F);
  float4*   boxes  = (float4*)(wsf + BOX_F);
  u32* hist   = (u32*)(ws + HIST_B);
  u32* ctrl   = (u32*)(ws + CTRL_B);
  u64* keybuf = (u64*)(ws + KEY_B);
  u64* sorted = (u64*)(ws + SORT_B);
  u64* validw = (u64*)(ws + VALW_B);
  u64* mask   = (u64*)(ws + MASK_B);
  u32* offTab = (u32*)(ws + OFFT_B);

  hipMemsetAsync(ws + HIST_B, 0, NBINS*4 + 256, stream);
  hipMemsetAsync(out + 2160000, 0, POST*4*sizeof(float), stream);

  pack_w1b<<<9216, 256, 0, stream>>>(w1, p12, p3);
  init_offtab<<<18, 256, 0, stream>>>(offTab);
  pack_wcl<<<129, 256, 0, stream>>>(wc, bc, wl, bl, wt64, b64);
  conv3x3_mfma<<<dim3(13, 25, 4), 256, 0, stream>>>(feat, p12, p3, offTab, b1, x);
  conv1x1<<<313, 256, 0, stream>>>(x, wt64, b64, out);
  decode<<<1407, 256, 0, stream>>>(out, anchor, scores, roi, hist);
  scan_hist<<<1, 256, 0, stream>>>(hist, ctrl);
  compact<<<1407, 256, 0, stream>>>(scores, ctrl, keybuf);
  sortk<<<1, 1024, 0, stream>>>(keybuf, ctrl, sorted);
  gather_topk<<<NW, 64, 0, stream>>>(sorted, roi, boxes, validw);
  nms_mask<<<dim3(NW, NW), 64, 0, stream>>>(boxes, mask);
  nms_scan<<<1, 64, 0, stream>>>(mask, validw, (const float*)boxes, out + 2160000);
}

// Round 6
// 1684.047 us; speedup vs baseline: 4.4118x; 4.4118x over previous
//
#include <hip/hip_runtime.h>

typedef unsigned long long u64;
typedef unsigned int u32;
typedef unsigned short ushort_t;

#define HH 200
#define WW 200
#define HWP 40000          // 200*200 pixels
#define NANCH 360000       // HWP * 9
#define PRE 6000
#define POST 300
#define NW 94              // 64-bit mask words per NMS row (ceil(6000/64))
#define NBINS 16384
#define KCAP 8192
#define LSTRIDE 40         // LDS row stride in ushorts (80B): 16B aligned, min-aliasing b128

typedef __attribute__((ext_vector_type(8))) short bf16x8;
typedef __attribute__((ext_vector_type(4))) float f32x4;

// ---------------- workspace layout (same footprint as round 1 + 18KB table) ----
static constexpr size_t X_F    = 0;                          // conv1 output x[512][40000] (+64 slack)
static constexpr size_t X_CNT  = 512ULL*HWP + 64;
static constexpr size_t W1B_F  = X_F + X_CNT;                // packed B planes 1+2: 4.72M ushorts = 2.36M floats
static constexpr size_t WT64_F = W1B_F + 4608ULL*512;        // packed cls/loc weights [512][64]
static constexpr size_t B64_F  = WT64_F + 512ULL*64;         // packed bias [64]
static constexpr size_t SC_F   = B64_F + 64;                 // scores [360000]
static constexpr size_t ROI_F  = SC_F + NANCH;               // decoded boxes [360000][4] (B plane 3 overlays pre-decode)
static constexpr size_t BOX_F  = ROI_F + 4ULL*NANCH;         // top-6000 boxes (pad 6016) [4]
static constexpr size_t FEND_F = BOX_F + 6016ULL*4;
static constexpr size_t HIST_B = ((FEND_F*4 + 255)/256)*256; // u32[16384]
static constexpr size_t CTRL_B = HIST_B + NBINS*4;           // u32[64]: [0]=cnt, [1]=cutoff bucket
static constexpr size_t KEY_B  = CTRL_B + 256;               // u64[8192] candidate keys
static constexpr size_t SORT_B = KEY_B + (size_t)KCAP*8;     // u64[6016] sorted keys
static constexpr size_t VALW_B = SORT_B + 6016ULL*8;         // u64[94] validity bits
static constexpr size_t MASK_B = ((VALW_B + NW*8 + 255)/256)*256; // u64[6000][94] NMS mask
static constexpr size_t OFFT_B = MASK_B + (size_t)PRE*NW*8;  // u32[4608] A-gather offset table
static constexpr size_t WS_END = OFFT_B + 4608ULL*4;         // ~103.5 MB total

// ---------------- helpers ----------------
__device__ __forceinline__ u32 fsort(float f) {
  u32 u = __float_as_uint(f);
  return (u & 0x80000000u) ? ~u : (u | 0x80000000u);
}
__device__ __forceinline__ int bucket_of(float s) {
  int b = (int)((s + 1.0f) * 8191.0f);
  return b < 0 ? 0 : (b > 16383 ? 16383 : b);
}

// ---------------- K0a: prepack w1 -> 3 exact bf16 slices, scattered into per-wave
// fragment order: p12[(((z*144+s)*2+wnb)*4+j)*1024 + p*512 + lane*8 + e]  (p in {0,1})
//                 p3 [(((z*144+s)*2+wnb)*4+j)*512  + lane*8 + e]
// so conv waves load B fragments directly from global, coalesced, no LDS.
__global__ void pack_w1b(const float* __restrict__ w1, ushort_t* __restrict__ p12,
                         ushort_t* __restrict__ p3) {
  int idx = blockIdx.x*256 + threadIdx.x;
  if (idx >= 512*4608) return;
  int och = idx / 4608, k = idx - (idx/4608)*4608;   // k = ci*9 + tap (reference order)
  float f = w1[idx];
  u32 u = __float_as_uint(f);
  float d = f - __uint_as_float(u & 0xffff0000u);
  u32 v = __float_as_uint(d);
  float e2 = d - __uint_as_float(v & 0xffff0000u);
  u32 w = __float_as_uint(e2);
  ushort_t h1 = (ushort_t)(u >> 16), h2 = (ushort_t)(v >> 16), h3 = (ushort_t)(w >> 16);
  int z = och >> 7, oz = och & 127;
  int wnb = oz >> 6, j = (oz >> 4) & 3, lm = oz & 15;
  int s = k >> 5, kk = k & 31, lg = kk >> 3, e = kk & 7;
  int lane = lg*16 + lm;
  size_t base = (((size_t)z*144 + s)*2 + wnb)*4 + j;
  p12[base*1024 +       lane*8 + e] = h1;
  p12[base*1024 + 512 + lane*8 + e] = h2;
  p3 [base*512  +       lane*8 + e] = h3;
}

// ---------------- K0c: A-gather offset table: offTab[k] = ((ci*HWP+dy*200+dx+256)<<4)|tap ----
__global__ void init_offtab(u32* __restrict__ offTab) {
  int k = blockIdx.x*256 + threadIdx.x;
  if (k >= 4608) return;
  int ci = k/9, tap = k - ci*9;
  int dy = tap/3 - 1, dx = tap - (tap/3)*3 - 1;
  int off = ci*HWP + dy*200 + dx;
  offTab[k] = ((u32)(off + 256) << 4) | (u32)tap;
}

// ---------------- K0b: pack wc(18)/wl(36) -> wt[ci][64] (zero-padded), bias[64] ----------------
__global__ void pack_wcl(const float* __restrict__ wc, const float* __restrict__ bc,
                         const float* __restrict__ wl, const float* __restrict__ bl,
                         float* __restrict__ wt, float* __restrict__ b64) {
  int idx = blockIdx.x*256 + threadIdx.x;
  if (idx < 512*64) {
    int ci = idx >> 6, o = idx & 63;
    float v = 0.f;
    if (o < 18) v = wc[o*512 + ci];
    else if (o < 54) v = wl[(o-18)*512 + ci];
    wt[idx] = v;
  } else if (idx < 512*64 + 64) {
    int o = idx - 512*64;
    float v = 0.f;
    if (o < 18) v = bc[o]; else if (o < 54) v = bl[o-18];
    b64[o] = v;
  }
}

// ---------------- K1: 3x3 conv 512->512 + ReLU, exact bf16x3 split, 6-product MFMA ----------
// A staged via LDS (3 planes, 30.7KB); B fragments loaded DIRECTLY from global
// (prepacked per-wave order, L1/L2/L3-resident). A-gather addresses via scalar table.
// launch_bounds(256,2): 256-VGPR budget -> NO SPILLS (R5's (256,5) cap spilled acc to
// scratch: 30 GB HBM round-trip, 7.4ms. Never cap below the live set.)
__global__ __launch_bounds__(256, 2) void conv3x3_mfma(const float* __restrict__ feat,
    const ushort_t* __restrict__ p12, const ushort_t* __restrict__ p3,
    const u32* __restrict__ offTab,
    const float* __restrict__ b1, float* __restrict__ xout) {
  __shared__ ushort_t A1[128*LSTRIDE], A2[128*LSTRIDE], A3[128*LSTRIDE];
  const int t = threadIdx.x;
  const int x0 = blockIdx.x*16, y0 = blockIdx.y*8;
  const int zi = blockIdx.z;
  const int ob = zi*128;
  const int m  = t & 127;                               // staging row (pixel)
  const int hU = __builtin_amdgcn_readfirstlane(t >> 7); // wave-uniform k-half selector
  const int myrow = m >> 4, mxcol = m & 15;
  const int py = y0 + myrow, px = x0 + mxcol;
  const int pixoff = py*200 + px;

  // per-thread 9-bit tap validity mask
  u32 vmask9 = 0;
  #pragma unroll
  for (int tap = 0; tap < 9; ++tap) {
    int dy = tap/3 - 1, dx = tap - (tap/3)*3 - 1;
    if ((unsigned)(py + dy) < 200u && (unsigned)(px + dx) < 200u) vmask9 |= (1u << tap);
  }

  f32x4 acc[4][4];
  #pragma unroll
  for (int i = 0; i < 4; ++i)
    #pragma unroll
    for (int j = 0; j < 4; ++j) acc[i][j] = (f32x4){0.f, 0.f, 0.f, 0.f};

  const int wave = t >> 6, lane = t & 63;
  const int wm = (wave & 1)*64, wnb = wave >> 1;
  const int lm = lane & 15, lg = lane >> 4;
  const u32* offp = offTab + 16*hU;

  for (int s = 0; s < 144; ++s) {
    // ---- B fragments: 12 coalesced 16B global loads straight to registers ----
    bf16x8 fb1[4], fb2[4], fb3[4];
    {
      const ushort_t* pb12 = p12 + ((((size_t)zi*144 + s)*2 + wnb)*4096) + lane*8;
      const ushort_t* pb3  = p3  + ((((size_t)zi*144 + s)*2 + wnb)*2048) + lane*8;
      #pragma unroll
      for (int j = 0; j < 4; ++j) {
        fb1[j] = *(const bf16x8*)(pb12 + j*1024);
        fb2[j] = *(const bf16x8*)(pb12 + j*1024 + 512);
        fb3[j] = *(const bf16x8*)(pb3  + j*512);
      }
    }
    // ---- A staging: 16 gathers (scalar-table addresses) -> 3 slices -> 6 ds_write_b128 ----
    {
      const u32* op = offp + s*32;
      u32 q1[8], q2[8], q3[8];
      #pragma unroll
      for (int j2 = 0; j2 < 8; ++j2) {
        float fv[2];
        #pragma unroll
        for (int e = 0; e < 2; ++e) {
          u32 ent = op[2*j2 + e];               // scalar load (wave-uniform index)
          int soff = (int)(ent >> 4) - 256;     // scalar
          u32 tap  = ent & 15u;                 // scalar
          bool ok  = ((vmask9 >> tap) & 1u) != 0;
          int voff = ok ? (soff + pixoff) : 0;
          float f = feat[voff];
          fv[e] = ok ? f : 0.f;
        }
        u32 u0 = __float_as_uint(fv[0]), u1 = __float_as_uint(fv[1]);
        q1[j2] = (u0 >> 16) | (u1 & 0xffff0000u);
        float d0 = fv[0] - __uint_as_float(u0 & 0xffff0000u);
        float d1 = fv[1] - __uint_as_float(u1 & 0xffff0000u);
        u32 v0 = __float_as_uint(d0), v1 = __float_as_uint(d1);
        q2[j2] = (v0 >> 16) | (v1 & 0xffff0000u);
        float e0 = d0 - __uint_as_float(v0 & 0xffff0000u);
        float e1 = d1 - __uint_as_float(v1 & 0xffff0000u);
        u32 w0 = __float_as_uint(e0), w1v = __float_as_uint(e1);
        q3[j2] = (w0 >> 16) | (w1v & 0xffff0000u);
      }
      *(uint4*)&A1[m*LSTRIDE + 16*hU    ] = make_uint4(q1[0], q1[1], q1[2], q1[3]);
      *(uint4*)&A1[m*LSTRIDE + 16*hU + 8] = make_uint4(q1[4], q1[5], q1[6], q1[7]);
      *(uint4*)&A2[m*LSTRIDE + 16*hU    ] = make_uint4(q2[0], q2[1], q2[2], q2[3]);
      *(uint4*)&A2[m*LSTRIDE + 16*hU + 8] = make_uint4(q2[4], q2[5], q2[6], q2[7]);
      *(uint4*)&A3[m*LSTRIDE + 16*hU    ] = make_uint4(q3[0], q3[1], q3[2], q3[3]);
      *(uint4*)&A3[m*LSTRIDE + 16*hU + 8] = make_uint4(q3[4], q3[5], q3[6], q3[7]);
    }
    __syncthreads();
    // ---- compute: 12 ds_read_b128 + 96 MFMA per wave ----
    bf16x8 fa1[4], fa2[4], fa3[4];
    #pragma unroll
    for (int i = 0; i < 4; ++i) {
      int ra = (wm + i*16 + lm)*LSTRIDE + lg*8;
      fa1[i] = *(const bf16x8*)&A1[ra];
      fa2[i] = *(const bf16x8*)&A2[ra];
      fa3[i] = *(const bf16x8*)&A3[ra];
    }
    #pragma unroll
    for (int i = 0; i < 4; ++i)
      #pragma unroll
      for (int j = 0; j < 4; ++j) {
        acc[i][j] = __builtin_amdgcn_mfma_f32_16x16x32_bf16(fa1[i], fb1[j], acc[i][j], 0, 0, 0);
        acc[i][j] = __builtin_amdgcn_mfma_f32_16x16x32_bf16(fa1[i], fb2[j], acc[i][j], 0, 0, 0);
        acc[i][j] = __builtin_amdgcn_mfma_f32_16x16x32_bf16(fa2[i], fb1[j], acc[i][j], 0, 0, 0);
        acc[i][j] = __builtin_amdgcn_mfma_f32_16x16x32_bf16(fa1[i], fb3[j], acc[i][j], 0, 0, 0);
        acc[i][j] = __builtin_amdgcn_mfma_f32_16x16x32_bf16(fa2[i], fb2[j], acc[i][j], 0, 0, 0);
        acc[i][j] = __builtin_amdgcn_mfma_f32_16x16x32_bf16(fa3[i], fb1[j], acc[i][j], 0, 0, 0);
      }
    __syncthreads();
  }

  // epilogue: bias + relu, store x[och][pixel]
  #pragma unroll
  for (int i = 0; i < 4; ++i) {
    int prow = wm + i*16 + lg*4;
    #pragma unroll
    for (int j = 0; j < 4; ++j) {
      int o = ob + wnb*64 + j*16 + lm;
      float bias = b1[o];
      #pragma unroll
      for (int r = 0; r < 4; ++r) {
        int p  = prow + r;
        int yy = y0 + (p >> 4), xx = x0 + (p & 15);
        if (xx < WW) {
          xout[(size_t)o*HWP + yy*200 + xx] = fmaxf(acc[i][j][r] + bias, 0.f);
        }
      }
    }
  }
}

// ---------------- K2: 1x1 convs (cls+loc) as GEMM [40000 x 64] = x^T[40000x512] * wt[512x64] ----
__global__ __launch_bounds__(256, 4) void conv1x1(const float* __restrict__ x,
                                                  const float* __restrict__ wt,
                                                  const float* __restrict__ bias,
                                                  float* __restrict__ out) {
  __shared__ float Xs[16*128];
  __shared__ float Ws[16*64];
  const int t = threadIdx.x;
  const int m0 = blockIdx.x*128;
  float acc[32];
  #pragma unroll
  for (int i = 0; i < 32; ++i) acc[i] = 0.f;
  const int mb = t & 15, nb = t >> 4;
  const int mm = t & 127, hh = t >> 7;
  const int nn = t & 63,  h2 = t >> 6;

  for (int kb = 0; kb < 512; kb += 16) {
    #pragma unroll
    for (int j = 0; j < 8; ++j) {
      int kk = hh + 2*j;
      Xs[kk*128 + mm] = x[(size_t)(kb+kk)*HWP + m0 + mm];
    }
    #pragma unroll
    for (int j = 0; j < 4; ++j) {
      int kk = h2 + 4*j;
      Ws[kk*64 + nn] = wt[(size_t)(kb+kk)*64 + nn];
    }
    __syncthreads();
    #pragma unroll
    for (int kk = 0; kk < 16; ++kk) {
      float av[8], bv[4];
      *(float4*)&av[0] = *(const float4*)&Xs[kk*128 + mb*8];
      *(float4*)&av[4] = *(const float4*)&Xs[kk*128 + mb*8 + 4];
      *(float4*)&bv[0] = *(const float4*)&Ws[kk*64 + nb*4];
      #pragma unroll
      for (int i = 0; i < 8; ++i)
        #pragma unroll
        for (int jj = 0; jj < 4; ++jj)
          acc[i*4+jj] = fmaf(av[i], bv[jj], acc[i*4+jj]);
    }
    __syncthreads();
  }

  #pragma unroll
  for (int jj = 0; jj < 4; ++jj) {
    int o = nb*4 + jj;
    float bv = bias[o];
    #pragma unroll
    for (int i = 0; i < 8; ++i) {
      int mm2 = m0 + mb*8 + i;
      if (mm2 < HWP) {
        float v = acc[i*4+jj] + bv;
        if (o < 18)       out[(size_t)mm2*18 + o] = v;               // pred_cls: [m][2a+c]
        else if (o < 54)  out[720000 + (size_t)mm2*36 + (o-18)] = v; // pred_loc: [m][4a+j]
      }
    }
  }
}

// ---------------- K3: decode boxes + score + histogram ----------------
__global__ void decode(const float* __restrict__ dout, const float* __restrict__ anchor,
                       float* __restrict__ scores, float4* __restrict__ roi, u32* __restrict__ hist) {
  int n = blockIdx.x*256 + threadIdx.x;
  if (n >= NANCH) return;
  int mq = n / 9;
  int a  = n - mq*9;
  float c0 = dout[(size_t)mq*18 + 2*a];
  float c1 = dout[(size_t)mq*18 + 2*a + 1];
  float score = 1.0f / (1.0f + expf(c0 - c1));  // == softmax[:,1]; monotone in (c1-c0)
  const float* lp = dout + 720000 + (size_t)mq*36 + 4*a;
  float l0 = lp[0], l1 = lp[1], l2 = lp[2], l3 = lp[3];
  float4 an = ((const float4*)anchor)[n];
  float aw = an.z - an.x, ah = an.w - an.y;
  float acx = (an.x + an.z)*0.5f, acy = (an.y + an.w)*0.5f;
  float cx = l0*aw + acx, cy = l1*ah + acy;
  float bw = expf(l2)*aw, bh = expf(l3)*ah;
  float x1 = fminf(fmaxf(cx - bw*0.5f, 0.f), 1.f);
  float y1 = fminf(fmaxf(cy - bh*0.5f, 0.f), 1.f);
  float x2 = fminf(fmaxf(cx + bw*0.5f, 0.f), 1.f);
  float y2 = fminf(fmaxf(cy + bh*0.5f, 0.f), 1.f);
  bool valid = ((y2 - y1) >= 0.016f) && ((x2 - x1) >= 0.016f);
  float sc = valid ? score : -1.0f;
  scores[n] = sc;
  roi[n] = make_float4(x1, y1, x2, y2);
  atomicAdd(&hist[bucket_of(sc)], 1u);
}

// ---------------- K4: find cutoff bucket B ----------------
__global__ void scan_hist(const u32* __restrict__ hist, u32* __restrict__ ctrl) {
  __shared__ u32 seg[256];
  int t = threadIdx.x;
  u32 s = 0;
  for (int b = 0; b < 64; ++b) s += hist[t*64 + b];
  seg[t] = s;
  __syncthreads();
  if (t == 0) {
    u32 cum = 0; int B = 0;
    for (int sg = 255; sg >= 0; --sg) {
      if (cum + seg[sg] >= PRE) {
        for (int b = sg*64 + 63; b >= sg*64; --b) {
          cum += hist[b];
          if (cum >= PRE) { B = b; break; }
        }
        break;
      }
      cum += seg[sg];
    }
    ctrl[1] = (u32)B;
  }
}

// ---------------- K5: compact candidates (bucket >= B) into keybuf ----------------
__global__ void compact(const float* __restrict__ scores, u32* __restrict__ ctrl, u64* __restrict__ keybuf) {
  int n = blockIdx.x*256 + threadIdx.x;
  if (n >= NANCH) return;
  float s = scores[n];
  int B = (int)ctrl[1];
  if (bucket_of(s) >= B) {
    u32 pos = atomicAdd(&ctrl[0], 1u);
    if (pos < KCAP) {
      keybuf[pos] = ((u64)fsort(s) << 32) | (u64)(0xFFFFFFFFu - (u32)n); // ties: lower n wins
    }
  }
}

// ---------------- K6: single-block bitonic sort of 8192 u64 keys, descending ----------------
__global__ __launch_bounds__(1024) void sortk(const u64* __restrict__ keybuf, const u32* __restrict__ ctrl,
                                              u64* __restrict__ sorted) {
  __shared__ u64 s[KCAP];
  int t = threadIdx.x;
  u32 cnt = ctrl[0]; if (cnt > KCAP) cnt = KCAP;
  for (int i = t; i < KCAP; i += 1024) s[i] = (i < (int)cnt) ? keybuf[i] : 0ULL;
  __syncthreads();
  for (int size = 2; size <= KCAP; size <<= 1) {
    for (int stride = size >> 1; stride > 0; stride >>= 1) {
      for (int w = t; w < KCAP/2; w += 1024) {
        int lo = ((w & ~(stride-1)) << 1) | (w & (stride-1));
        int hi = lo + stride;
        bool desc = ((lo & size) == 0);
        u64 a = s[lo], b = s[hi];
        if ((a < b) == desc) { s[lo] = b; s[hi] = a; }
      }
      __syncthreads();
    }
  }
  for (int i = t; i < 6016; i += 1024) sorted[i] = s[i];
}

// ---------------- K6b: gather top-6000 boxes + validity bits ----------------
__global__ void gather_topk(const u64* __restrict__ sorted, const float4* __restrict__ roi,
                            float4* __restrict__ boxes, u64* __restrict__ validw) {
  int i = blockIdx.x*64 + threadIdx.x;
  bool valid = false;
  float4 b = make_float4(0.f, 0.f, 0.f, 0.f);
  if (i < PRE) {
    u64 k = sorted[i];
    if (k) {
      u32 n = 0xFFFFFFFFu - (u32)(k & 0xFFFFFFFFu);
      if (n < NANCH) { b = roi[n]; valid = (k >> 63) != 0; }
    }
  }
  boxes[i] = b;
  u64 bal = __ballot(valid);
  if (threadIdx.x == 0) validw[blockIdx.x] = bal;
}

// ---------------- K7: NMS suppression bitmask ----------------
__global__ void nms_mask(const float4* __restrict__ boxes, u64* __restrict__ mask) {
  int bi = blockIdx.y, bj = blockIdx.x;
  int t = threadIdx.x;
  int i = bi*64 + t;
  if (bj < bi) {
    if (i < PRE) mask[(size_t)i*NW + bj] = 0ULL;
    return;
  }
  __shared__ float4 cb[64];
  int j0 = bj*64;
  cb[t] = boxes[j0 + t];
  __syncthreads();
  if (i >= PRE) return;
  float4 b = boxes[i];
  float area_i = (b.z - b.x) * (b.w - b.y);
  u64 bits = 0;
  #pragma unroll 4
  for (int jj = 0; jj < 64; ++jj) {
    int j = j0 + jj;
    float4 c = cb[jj];
    float xx1 = fmaxf(b.x, c.x), yy1 = fmaxf(b.y, c.y);
    float xx2 = fminf(b.z, c.z), yy2 = fminf(b.w, c.w);
    float inter = fmaxf(xx2 - xx1, 0.f) * fmaxf(yy2 - yy1, 0.f);
    float area_j = (c.z - c.x) * (c.w - c.y);
    float iou = inter / (area_i + area_j - inter + 1e-12f);
    if (iou > 0.7f && j > i) bits |= (1ULL << jj);
  }
  mask[(size_t)i*NW + bj] = bits;
}

// ---------------- K8: sequential greedy scan + emit first 300 kept boxes ----------------
__global__ void nms_scan(const u64* __restrict__ mask, const u64* __restrict__ validw,
                         const float* __restrict__ boxes, float* __restrict__ rois) {
  int lane = threadIdx.x;
  u64 r0 = ~validw[lane];
  u64 r1 = (lane < NW-64) ? ~validw[64 + lane] : ~0ULL;
  int kept = 0;
  u64 m0 = mask[lane];
  u64 m1 = (lane < NW-64) ? mask[64 + lane] : 0ULL;
  for (int i = 0; i < PRE; ++i) {
    int wi = i >> 6;
    u64 w0 = __shfl(r0, wi & 63);
    u64 w1 = __shfl(r1, wi & 63);
    u64 wv = (wi < 64) ? w0 : w1;
    if (!((wv >> (i & 63)) & 1ULL)) {
      if (lane < 4) rois[kept*4 + lane] = boxes[(size_t)i*4 + lane];
      kept++;
      if (kept >= POST) break;
      r0 |= m0;
      if (lane < NW-64) r1 |= m1;
    }
    if (i + 1 < PRE) {
      m0 = mask[(size_t)(i+1)*NW + lane];
      m1 = (lane < NW-64) ? mask[(size_t)(i+1)*NW + 64 + lane] : 0ULL;
    }
  }
}

extern "C" void kernel_launch(void* const* d_in, const int* in_sizes, int n_in,
                              void* d_out, int out_size, void* d_ws, size_t ws_size,
                              hipStream_t stream) {
  const float* feat   = (const float*)d_in[0];
  const float* anchor = (const float*)d_in[1];
  const float* w1     = (const float*)d_in[2];
  const float* b1     = (const float*)d_in[3];
  const float* wc     = (const float*)d_in[4];
  const float* bc     = (const float*)d_in[5];
  const float* wl     = (const float*)d_in[6];
  const float* bl     = (const float*)d_in[7];
  float* out = (float*)d_out;
  char*  ws  = (char*)d_ws;
  float* wsf = (float*)d_ws;

  if (ws_size < WS_END) return;  // need ~103.5 MB

  float*    x      = wsf + X_F;
  ushort_t* p12    = (ushort_t*)(wsf + W1B_F);   // packed B planes 1+2 (9.44 MB)
  ushort_t* p3     = (ushort_t*)(wsf + ROI_F);   // packed B plane 3 overlays roi (dead pre-decode)
  float*    wt64   = wsf + WT64_F;
  float*    b64    = wsf + B64_F;
  float*    scores = wsf + SC_F;
  float4*   roi    = (float4*)(wsf + ROI_F);
  float4*   boxes  = (float4*)(wsf + BOX_F);
  u32* hist   = (u32*)(ws + HIST_B);
  u32* ctrl   = (u32*)(ws + CTRL_B);
  u64* keybuf = (u64*)(ws + KEY_B);
  u64* sorted = (u64*)(ws + SORT_B);
  u64* validw = (u64*)(ws + VALW_B);
  u64* mask   = (u64*)(ws + MASK_B);
  u32* offTab = (u32*)(ws + OFFT_B);

  hipMemsetAsync(ws + HIST_B, 0, NBINS*4 + 256, stream);
  hipMemsetAsync(out + 2160000, 0, POST*4*sizeof(float), stream);

  pack_w1b<<<9216, 256, 0, stream>>>(w1, p12, p3);
  init_offtab<<<18, 256, 0, stream>>>(offTab);
  pack_wcl<<<129, 256, 0, stream>>>(wc, bc, wl, bl, wt64, b64);
  conv3x3_mfma<<<dim3(13, 25, 4), 256, 0, stream>>>(feat, p12, p3, offTab, b1, x);
  conv1x1<<<313, 256, 0, stream>>>(x, wt64, b64, out);
  decode<<<1407, 256, 0, stream>>>(out, anchor, scores, roi, hist);
  scan_hist<<<1, 256, 0, stream>>>(hist, ctrl);
  compact<<<1407, 256, 0, stream>>>(scores, ctrl, keybuf);
  sortk<<<1, 1024, 0, stream>>>(keybuf, ctrl, sorted);
  gather_topk<<<NW, 64, 0, stream>>>(sorted, roi, boxes, validw);
  nms_mask<<<dim3(NW, NW), 64, 0, stream>>>(boxes, mask);
  nms_scan<<<1, 64, 0, stream>>>(mask, validw, (const float*)boxes, out + 2160000);
}